// Round 7
// baseline (107.584 us; speedup 1.0000x reference)
//
#include <hip/hip_runtime.h>
#include <math.h>

#define NUM_T   1000
#define NUM_R   8
#define NBINS   200
#define FPB     2                       // frames per block -> grid 8*500=4000
#define TTSZ    224                     // padded threshold table (inf tail)
#define TYSTR   218                     // rows per type (even!): 200 bins + 17 dump
#define HWORDS  5232                    // 327 row-pairs x 16 cols (rows 0..653)

__device__ __forceinline__ float approx_sqrt(float x) {
    float r; asm("v_sqrt_f32 %0, %1" : "=v"(r) : "v"(x)); return r;
}
__device__ __forceinline__ float fract_(float x) {
#if __has_builtin(__builtin_amdgcn_fractf)
    return __builtin_amdgcn_fractf(x);
#else
    return x - floorf(x);
#endif
}

// ---------------------------------------------------------------------------
// Bit-exact binning on squared distances (validated R1-R4, absmax 3.906e-3):
//   TT[k] = min{s : sqrtf(s) >= bins[k]}; TT[200] = Tp (d<=10 edge).
//   Fast path k=(int)z, z=v_sqrt(400s), exact unless frac(z) within +-2e-4
//   of an integer (boundary-image analysis R3). Ambiguous -> whole-wave-vote
//   slow path: k += (s>=TT[k+1]) - (s<TT[k]) (no-op for exact lanes);
//   k<0 (s<TT[0], incl. d==0 -- always ambiguous since z<3e-5) -> k=216.
//   No explicit range test: d>10 lands at k=200..215 (z<=215.2); k=200..216
//   are PER-TYPE dump rows, never flushed.
// Histogram: bank-aligned per-lane-column u16 counters.
//   Physical row pr = type*218 + k  (218 even => pr&1 == k&1; each type's
//   dump rows 200..216 are private -- R5's bug was a 200-row stride, which
//   collided OO dumps with HH bins 0..16). word = (pr>>1)*16 + (tid&15),
//   half = k&1. Bank = col + 16*((k>>1)&1): columns never share banks; the
//   4 lanes per column split over 2 banks (~2-way = free).
//   atomicAdd(word, W << 16*half); u16 cannot overflow (<~2e3 per word/block).
// Pair enumeration (symmetric types once, weight 2) as R4:
//   OO/H0H0/H1H1 rotations (dup'd arrays, k=q+1+4*it, k=32 half-covered),
//   HH cross H0xH1 uniform-j w2, HO uniform-O read feeds both H rows w1.
// ---------------------------------------------------------------------------
__global__ __launch_bounds__(256) void rdf_hist_kernel(
    const float* __restrict__ radii,      // [T][R][192][3]
    const float* __restrict__ lat,        // [3]
    unsigned int* __restrict__ gh)        // [R][3][200]
{
    #pragma clang fp contract(off)
    __shared__ float4 posOx[96], posH0[96], posH1[96];
    __shared__ float TT[TTSZ];
    __shared__ unsigned int hist[HWORDS];

    const int tid = threadIdx.x;

    if (tid < TTSZ) {
        float v;
        if (tid <= 200) {
            float b;
            if (tid < NBINS) {
                const double step = (10.0 - 1e-6) / 200.0;
                b = (float)(1e-6 + (double)tid * step);
            } else {
                b = __uint_as_float(__float_as_uint(10.0f) + 1u); // nextafter(10,inf)
            }
            unsigned lo = 0u, hi = 0x7F800000u;
            while (lo < hi) {
                unsigned mid = (lo + hi) >> 1;
                if (sqrtf(__uint_as_float(mid)) >= b) hi = mid; else lo = mid + 1;
            }
            v = __uint_as_float(lo);
        } else {
            v = __uint_as_float(0x7F800000u);   // +inf padding
        }
        TT[tid] = v;
    }
    for (int i = tid; i < HWORDS; i += 256) hist[i] = 0u;

    const float Lx = lat[0], Ly = lat[1], Lz = lat[2];
    __syncthreads();

    const int col = tid & 15;

// TBASE = col + (type*TYSTR/2)<<4, precomputed per section.
#define PAIR(PI, PJ, TBASE, W)                                               \
    {                                                                        \
        float tx = (PI).x - (PJ).x;                                          \
        float ty = (PI).y - (PJ).y;                                          \
        float tz = (PI).z - (PJ).z;                                          \
        float ax = fminf(fabsf(tx), Lx - fabsf(tx));                         \
        float ay = fminf(fabsf(ty), Ly - fabsf(ty));                         \
        float az = fminf(fabsf(tz), Lz - fabsf(tz));                         \
        float s  = (ax*ax + ay*ay) + az*az;                                  \
        float z  = approx_sqrt(s * 400.0f);                                  \
        int   k  = (int)z;                                                   \
        float m  = fract_(z);                                                \
        bool amb = fabsf(m - 0.5f) > 0.49980f;                               \
        if (__builtin_expect(__any(amb), 0)) {                               \
            float tlo = TT[k], thi = TT[k + 1];                              \
            k += ((s >= thi) ? 1 : 0) - ((s < tlo) ? 1 : 0);                 \
            if (k < 0) k = 216;                                              \
        }                                                                    \
        int w = (TBASE) + ((k >> 1) << 4);                                   \
        unsigned val = (unsigned)(W) << ((k & 1) << 4);                      \
        atomicAdd(&hist[w], val);                                            \
    }

    const int rep   = blockIdx.x & (NUM_R - 1);
    const int chunk = blockIdx.x / NUM_R;
    const int l     = tid & 63;
    const int q     = tid >> 6;               // wave id 0..3 (wave-uniform)
    const int tbOO  = col;                    // type 0: rows   0..217
    const int tbHH  = col + (109 << 4);       // type 1: rows 218..435
    const int tbHO  = col + (218 << 4);       // type 2: rows 436..653

    // prefetch frame 0 raw coords
    float rvx = 0.f, rvy = 0.f, rvz = 0.f;
    {
        const float* s0 = radii + ((size_t)(chunk * FPB) * NUM_R + rep) * (192 * 3);
        if (tid < 192) { rvx = s0[tid*3+0]; rvy = s0[tid*3+1]; rvz = s0[tid*3+2]; }
    }

    #pragma unroll 1
    for (int f = 0; f < FPB; ++f) {
        __syncthreads();
        if (tid < 192) {
            float ux = rvx / Lx; ux -= floorf(ux);
            float uy = rvy / Ly; uy -= floorf(uy);
            float uz = rvz / Lz; uz -= floorf(uz);
            float4 p = make_float4(ux*Lx, uy*Ly, uz*Lz, 0.0f);
            if (tid < 64)       { posOx[tid] = p;  if (tid < 32) posOx[tid+64] = p; }
            else if (tid < 128) { int h = tid-64;  posH0[h] = p; if (h < 32) posH0[h+64] = p; }
            else                { int h = tid-128; posH1[h] = p; if (h < 32) posH1[h+64] = p; }
        }
        __syncthreads();

        if (f + 1 < FPB && tid < 192) {   // prefetch next frame during compute
            const float* s1 = radii + ((size_t)(chunk * FPB + f + 1) * NUM_R + rep) * (192 * 3);
            rvx = s1[tid*3+0]; rvy = s1[tid*3+1]; rvz = s1[tid*3+2];
        }

        const float4 piO = posOx[l];
        const float4 pi0 = posH0[l];
        const float4 pi1 = posH1[l];
        const int jb = l + q + 1;

        // ---- O-O rotation: k = q+1+4*it; k=32 (q=3,it=7) half-covered ----
        #pragma unroll
        for (int it = 0; it < 7; ++it) { float4 pj = posOx[jb + 4*it]; PAIR(piO, pj, tbOO, 2u); }
        if (q < 3 || l < 32)           { float4 pj = posOx[jb + 28];   PAIR(piO, pj, tbOO, 2u); }

        // ---- H0 diag rotation ----
        #pragma unroll
        for (int it = 0; it < 7; ++it) { float4 pj = posH0[jb + 4*it]; PAIR(pi0, pj, tbHH, 2u); }
        if (q < 3 || l < 32)           { float4 pj = posH0[jb + 28];   PAIR(pi0, pj, tbHH, 2u); }

        // ---- H1 diag rotation ----
        #pragma unroll
        for (int it = 0; it < 7; ++it) { float4 pj = posH1[jb + 4*it]; PAIR(pi1, pj, tbHH, 2u); }
        if (q < 3 || l < 32)           { float4 pj = posH1[jb + 28];   PAIR(pi1, pj, tbHH, 2u); }

        // ---- HH cross (H0 x H1), weight 2, wave-uniform j ----
        #pragma unroll 4
        for (int jj = 0; jj < 16; ++jj) {
            float4 pj = posH1[q * 16 + jj];
            PAIR(pi0, pj, tbHH, 2u);
        }
        // ---- H-O ordered, weight 1: one uniform O read feeds both H rows ----
        #pragma unroll 4
        for (int jj = 0; jj < 16; ++jj) {
            float4 pj = posOx[q * 16 + jj];
            PAIR(pi0, pj, tbHO, 1u);
            PAIR(pi1, pj, tbHO, 1u);
        }
    }
#undef PAIR

    __syncthreads();
    // flush logical rows (type p, bin b) -> physical row p*218 + b; dump rows
    // (k>=200) are skipped by construction. Column start rotated per row so
    // wave lanes stay conflict-free (<=2-way).
    for (int idx = tid; idx < 3 * NBINS; idx += 256) {
        const int p    = idx / 200;
        const int b    = idx - p * 200;
        const int pr   = p * TYSTR + b;
        const int base = (pr >> 1) << 4;
        const int sh   = (b & 1) << 4;
        const int c0   = idx & 15;
        unsigned sum = 0;
        #pragma unroll
        for (int c = 0; c < 16; ++c) {
            unsigned wrd = hist[base + ((c0 + c) & 15)];
            sum += (wrd >> sh) & 0xFFFFu;
        }
        if (sum) atomicAdd(&gh[rep * 3 * NBINS + idx], sum);
    }
}

// ---------------------------------------------------------------------------
__global__ __launch_bounds__(256) void rdf_final_kernel(
    const unsigned int* __restrict__ gh,  // [R][3][200]
    const float* __restrict__ gt,         // [3][200]
    const float* __restrict__ lat,        // [3]
    float* __restrict__ out)              // [R][600] then [R] maxmae
{
    #pragma clang fp contract(off)
    const int rep = blockIdx.x;
    const int tid = threadIdx.x;
    __shared__ float bins[NBINS + 1];
    __shared__ float red[256];

    for (int i = tid; i <= NBINS; i += 256) {
        const double step = (10.0 - 1e-6) / 200.0;
        bins[i] = (i == NBINS) ? 10.0f : (float)(1e-6 + (double)i * step);
    }
    __syncthreads();

    const float vol = (lat[0] * lat[1]) * lat[2];
    const float C   = 4.18879020478639053f;   // float(4/3*pi)
    const int npairs[3] = { NUM_T*64*64, NUM_T*128*128, NUM_T*128*64 };

    float maxmae = -3.0e38f;
    for (int p = 0; p < 3; ++p) {
        float diff = 0.0f;
        if (tid < NBINS) {
            float b0 = bins[tid], b1 = bins[tid + 1];
            float shell = C * (b1*b1*b1 - b0*b0*b0);
            float rho = (float)npairs[p] / vol;
            float g = (float)gh[(rep*3 + p)*NBINS + tid] / (rho * shell);
            out[rep*3*NBINS + p*NBINS + tid] = g;
            diff = fabsf(g - gt[p*NBINS + tid]);
        }
        red[tid] = diff;
        __syncthreads();
        for (int s = 128; s > 0; s >>= 1) {
            if (tid < s) red[tid] += red[tid + s];
            __syncthreads();
        }
        if (tid == 0) {
            float mae = 10.0f * (red[0] / 200.0f);
            if (mae > maxmae) maxmae = mae;
        }
        __syncthreads();
    }
    if (tid == 0) out[NUM_R*3*NBINS + rep] = maxmae;
}

// ---------------------------------------------------------------------------
extern "C" void kernel_launch(void* const* d_in, const int* in_sizes, int n_in,
                              void* d_out, int out_size, void* d_ws, size_t ws_size,
                              hipStream_t stream) {
    const float* radii = (const float*)d_in[0];
    const float* lat   = (const float*)d_in[1];
    const float* gt    = (const float*)d_in[2];
    unsigned int* gh   = (unsigned int*)d_ws;

    hipMemsetAsync(gh, 0, NUM_R * 3 * NBINS * sizeof(unsigned int), stream);

    dim3 grid(NUM_R * (NUM_T / FPB));     // 8 * 500 = 4000 blocks
    hipLaunchKernelGGL(rdf_hist_kernel, grid, dim3(256), 0, stream,
                       radii, lat, gh);
    hipLaunchKernelGGL(rdf_final_kernel, dim3(NUM_R), dim3(256), 0, stream,
                       gh, gt, lat, (float*)d_out);
}

// Round 8
// 101.031 us; speedup vs baseline: 1.0649x; 1.0649x over previous
//
#include <hip/hip_runtime.h>
#include <math.h>

#define NUM_T   1000
#define NUM_R   8
#define NBINS   200
#define FPB     2                       // frames per block -> grid 8*500=4000
#define TTSZ    224                     // padded threshold table (inf tail)
#define TYSTR   218                     // rows per type (even!): 200 bins + 17 dump
#define NCOL    8                       // histogram columns (tid&7)
#define HWORDS  2616                    // 327 row-pairs x 8 cols (rows 0..653)

__device__ __forceinline__ float approx_sqrt(float x) {
    float r; asm("v_sqrt_f32 %0, %1" : "=v"(r) : "v"(x)); return r;
}
__device__ __forceinline__ float fract_(float x) {
#if __has_builtin(__builtin_amdgcn_fractf)
    return __builtin_amdgcn_fractf(x);
#else
    return x - floorf(x);
#endif
}

// ---------------------------------------------------------------------------
// Bit-exact binning on squared distances (validated R1-R6, absmax 3.906e-3):
//   TT[k] = min{s : sqrtf(s) >= bins[k]}; TT[200] = Tp (d<=10 edge).
//   Fast path k=(int)z, z=v_sqrt(400s), exact unless frac(z) within +-2e-4
//   of an integer (boundary-image analysis R3). Ambiguous -> whole-wave-vote
//   slow path: k += (s>=TT[k+1]) - (s<TT[k]) (no-op for exact lanes);
//   k<0 (s<TT[0], incl. d==0 -- always ambiguous since z<3e-5) -> k=216.
//   No explicit range test: d>10 lands at k=200..215 (z<=215.2); k=200..216
//   are PER-TYPE dump rows (TYSTR=218 stride, R6 fix), never flushed.
// Histogram: bank-aligned per-lane-column u16 counters, NCOL=8 (R7: halves
//   LDS 26.6->16.0 KB so 8 blocks/CU resident = 32 waves, occupancy lever).
//   word = (pr>>1)*8 + (tid&7); bank = col + 8*((pr>>1)&3): each column's
//   8 lanes spread over 4 private banks (~2/bank, free); columns disjoint.
//   atomicAdd(word, W << 16*(k&1)); u16 cannot overflow (<57k/block total).
// Pair enumeration (symmetric types once, weight 2) as R4/R6:
//   OO/H0H0/H1H1 rotations (dup'd arrays, k=q+1+4*it, k=32 half-covered),
//   HH cross H0xH1 uniform-j w2, HO uniform-O read feeds both H rows w1.
// ---------------------------------------------------------------------------
__global__ __launch_bounds__(256) void rdf_hist_kernel(
    const float* __restrict__ radii,      // [T][R][192][3]
    const float* __restrict__ lat,        // [3]
    unsigned int* __restrict__ gh)        // [R][3][200]
{
    #pragma clang fp contract(off)
    __shared__ float4 posOx[96], posH0[96], posH1[96];
    __shared__ float TT[TTSZ];
    __shared__ unsigned int hist[HWORDS];

    const int tid = threadIdx.x;

    if (tid < TTSZ) {
        float v;
        if (tid <= 200) {
            float b;
            if (tid < NBINS) {
                const double step = (10.0 - 1e-6) / 200.0;
                b = (float)(1e-6 + (double)tid * step);
            } else {
                b = __uint_as_float(__float_as_uint(10.0f) + 1u); // nextafter(10,inf)
            }
            unsigned lo = 0u, hi = 0x7F800000u;
            while (lo < hi) {
                unsigned mid = (lo + hi) >> 1;
                if (sqrtf(__uint_as_float(mid)) >= b) hi = mid; else lo = mid + 1;
            }
            v = __uint_as_float(lo);
        } else {
            v = __uint_as_float(0x7F800000u);   // +inf padding
        }
        TT[tid] = v;
    }
    for (int i = tid; i < HWORDS; i += 256) hist[i] = 0u;

    const float Lx = lat[0], Ly = lat[1], Lz = lat[2];
    __syncthreads();

    const int col = tid & (NCOL - 1);

// TBASE = col + (type*TYSTR/2)*NCOL, precomputed per section.
#define PAIR(PI, PJ, TBASE, W)                                               \
    {                                                                        \
        float tx = (PI).x - (PJ).x;                                          \
        float ty = (PI).y - (PJ).y;                                          \
        float tz = (PI).z - (PJ).z;                                          \
        float ax = fminf(fabsf(tx), Lx - fabsf(tx));                         \
        float ay = fminf(fabsf(ty), Ly - fabsf(ty));                         \
        float az = fminf(fabsf(tz), Lz - fabsf(tz));                         \
        float s  = (ax*ax + ay*ay) + az*az;                                  \
        float z  = approx_sqrt(s * 400.0f);                                  \
        int   k  = (int)z;                                                   \
        float m  = fract_(z);                                                \
        bool amb = fabsf(m - 0.5f) > 0.49980f;                               \
        if (__builtin_expect(__any(amb), 0)) {                               \
            float tlo = TT[k], thi = TT[k + 1];                              \
            k += ((s >= thi) ? 1 : 0) - ((s < tlo) ? 1 : 0);                 \
            if (k < 0) k = 216;                                              \
        }                                                                    \
        int w = (TBASE) + ((k >> 1) << 3);                                   \
        unsigned val = (unsigned)(W) << ((k & 1) << 4);                      \
        atomicAdd(&hist[w], val);                                            \
    }

    const int rep   = blockIdx.x & (NUM_R - 1);
    const int chunk = blockIdx.x / NUM_R;
    const int l     = tid & 63;
    const int q     = tid >> 6;               // wave id 0..3 (wave-uniform)
    const int tbOO  = col;                    // type 0: rows   0..217
    const int tbHH  = col + 109 * NCOL;       // type 1: rows 218..435
    const int tbHO  = col + 218 * NCOL;       // type 2: rows 436..653

    // prefetch frame 0 raw coords
    float rvx = 0.f, rvy = 0.f, rvz = 0.f;
    {
        const float* s0 = radii + ((size_t)(chunk * FPB) * NUM_R + rep) * (192 * 3);
        if (tid < 192) { rvx = s0[tid*3+0]; rvy = s0[tid*3+1]; rvz = s0[tid*3+2]; }
    }

    #pragma unroll 1
    for (int f = 0; f < FPB; ++f) {
        __syncthreads();
        if (tid < 192) {
            float ux = rvx / Lx; ux -= floorf(ux);
            float uy = rvy / Ly; uy -= floorf(uy);
            float uz = rvz / Lz; uz -= floorf(uz);
            float4 p = make_float4(ux*Lx, uy*Ly, uz*Lz, 0.0f);
            if (tid < 64)       { posOx[tid] = p;  if (tid < 32) posOx[tid+64] = p; }
            else if (tid < 128) { int h = tid-64;  posH0[h] = p; if (h < 32) posH0[h+64] = p; }
            else                { int h = tid-128; posH1[h] = p; if (h < 32) posH1[h+64] = p; }
        }
        __syncthreads();

        if (f + 1 < FPB && tid < 192) {   // prefetch next frame during compute
            const float* s1 = radii + ((size_t)(chunk * FPB + f + 1) * NUM_R + rep) * (192 * 3);
            rvx = s1[tid*3+0]; rvy = s1[tid*3+1]; rvz = s1[tid*3+2];
        }

        const float4 piO = posOx[l];
        const float4 pi0 = posH0[l];
        const float4 pi1 = posH1[l];
        const int jb = l + q + 1;

        // ---- O-O rotation: k = q+1+4*it; k=32 (q=3,it=7) half-covered ----
        #pragma unroll
        for (int it = 0; it < 7; ++it) { float4 pj = posOx[jb + 4*it]; PAIR(piO, pj, tbOO, 2u); }
        if (q < 3 || l < 32)           { float4 pj = posOx[jb + 28];   PAIR(piO, pj, tbOO, 2u); }

        // ---- H0 diag rotation ----
        #pragma unroll
        for (int it = 0; it < 7; ++it) { float4 pj = posH0[jb + 4*it]; PAIR(pi0, pj, tbHH, 2u); }
        if (q < 3 || l < 32)           { float4 pj = posH0[jb + 28];   PAIR(pi0, pj, tbHH, 2u); }

        // ---- H1 diag rotation ----
        #pragma unroll
        for (int it = 0; it < 7; ++it) { float4 pj = posH1[jb + 4*it]; PAIR(pi1, pj, tbHH, 2u); }
        if (q < 3 || l < 32)           { float4 pj = posH1[jb + 28];   PAIR(pi1, pj, tbHH, 2u); }

        // ---- HH cross (H0 x H1), weight 2, wave-uniform j ----
        #pragma unroll 4
        for (int jj = 0; jj < 16; ++jj) {
            float4 pj = posH1[q * 16 + jj];
            PAIR(pi0, pj, tbHH, 2u);
        }
        // ---- H-O ordered, weight 1: one uniform O read feeds both H rows ----
        #pragma unroll 4
        for (int jj = 0; jj < 16; ++jj) {
            float4 pj = posOx[q * 16 + jj];
            PAIR(pi0, pj, tbHO, 1u);
            PAIR(pi1, pj, tbHO, 1u);
        }
    }
#undef PAIR

    __syncthreads();
    // flush logical rows (type p, bin b) -> physical row p*218 + b; dump rows
    // (k>=200) skipped by construction. Column start rotated per row so wave
    // lanes stay conflict-free.
    for (int idx = tid; idx < 3 * NBINS; idx += 256) {
        const int p    = idx / 200;
        const int b    = idx - p * 200;
        const int pr   = p * TYSTR + b;
        const int base = (pr >> 1) << 3;
        const int sh   = (b & 1) << 4;
        const int c0   = idx & (NCOL - 1);
        unsigned sum = 0;
        #pragma unroll
        for (int c = 0; c < NCOL; ++c) {
            unsigned wrd = hist[base + ((c0 + c) & (NCOL - 1))];
            sum += (wrd >> sh) & 0xFFFFu;
        }
        if (sum) atomicAdd(&gh[rep * 3 * NBINS + idx], sum);
    }
}

// ---------------------------------------------------------------------------
__global__ __launch_bounds__(256) void rdf_final_kernel(
    const unsigned int* __restrict__ gh,  // [R][3][200]
    const float* __restrict__ gt,         // [3][200]
    const float* __restrict__ lat,        // [3]
    float* __restrict__ out)              // [R][600] then [R] maxmae
{
    #pragma clang fp contract(off)
    const int rep = blockIdx.x;
    const int tid = threadIdx.x;
    __shared__ float bins[NBINS + 1];
    __shared__ float red[256];

    for (int i = tid; i <= NBINS; i += 256) {
        const double step = (10.0 - 1e-6) / 200.0;
        bins[i] = (i == NBINS) ? 10.0f : (float)(1e-6 + (double)i * step);
    }
    __syncthreads();

    const float vol = (lat[0] * lat[1]) * lat[2];
    const float C   = 4.18879020478639053f;   // float(4/3*pi)
    const int npairs[3] = { NUM_T*64*64, NUM_T*128*128, NUM_T*128*64 };

    float maxmae = -3.0e38f;
    for (int p = 0; p < 3; ++p) {
        float diff = 0.0f;
        if (tid < NBINS) {
            float b0 = bins[tid], b1 = bins[tid + 1];
            float shell = C * (b1*b1*b1 - b0*b0*b0);
            float rho = (float)npairs[p] / vol;
            float g = (float)gh[(rep*3 + p)*NBINS + tid] / (rho * shell);
            out[rep*3*NBINS + p*NBINS + tid] = g;
            diff = fabsf(g - gt[p*NBINS + tid]);
        }
        red[tid] = diff;
        __syncthreads();
        for (int s = 128; s > 0; s >>= 1) {
            if (tid < s) red[tid] += red[tid + s];
            __syncthreads();
        }
        if (tid == 0) {
            float mae = 10.0f * (red[0] / 200.0f);
            if (mae > maxmae) maxmae = mae;
        }
        __syncthreads();
    }
    if (tid == 0) out[NUM_R*3*NBINS + rep] = maxmae;
}

// ---------------------------------------------------------------------------
extern "C" void kernel_launch(void* const* d_in, const int* in_sizes, int n_in,
                              void* d_out, int out_size, void* d_ws, size_t ws_size,
                              hipStream_t stream) {
    const float* radii = (const float*)d_in[0];
    const float* lat   = (const float*)d_in[1];
    const float* gt    = (const float*)d_in[2];
    unsigned int* gh   = (unsigned int*)d_ws;

    hipMemsetAsync(gh, 0, NUM_R * 3 * NBINS * sizeof(unsigned int), stream);

    dim3 grid(NUM_R * (NUM_T / FPB));     // 8 * 500 = 4000 blocks
    hipLaunchKernelGGL(rdf_hist_kernel, grid, dim3(256), 0, stream,
                       radii, lat, gh);
    hipLaunchKernelGGL(rdf_final_kernel, dim3(NUM_R), dim3(256), 0, stream,
                       gh, gt, lat, (float*)d_out);
}